// Round 1
// baseline (687.351 us; speedup 1.0000x reference)
//
#include <hip/hip_runtime.h>

typedef __bf16 bf16x8 __attribute__((ext_vector_type(8)));
typedef float f32x4 __attribute__((ext_vector_type(4)));
typedef unsigned short u16x8 __attribute__((ext_vector_type(8)));
typedef unsigned short u16x4 __attribute__((ext_vector_type(4)));

__device__ __forceinline__ unsigned short f2bf(float f) {
    union { float f; unsigned int u; } a; a.f = f;
    unsigned int u = a.u;
    unsigned int r = (u + 0x7FFFu + ((u >> 16) & 1u)) >> 16;  // RNE
    return (unsigned short)r;
}

// ---------------- LayerNorm: fp32 in -> bf16 out (E=1024, one row per block) ----------------
__global__ __launch_bounds__(256) void ln_kernel(
    const float* __restrict__ x, const float* __restrict__ g,
    const float* __restrict__ b, unsigned short* __restrict__ out)
{
    const int row = blockIdx.x;
    const int tid = threadIdx.x;
    const float4 v = reinterpret_cast<const float4*>(x + (size_t)row * 1024)[tid];
    float s = v.x + v.y + v.z + v.w;
    float q = v.x * v.x + v.y * v.y + v.z * v.z + v.w * v.w;
#pragma unroll
    for (int off = 32; off >= 1; off >>= 1) {
        s += __shfl_xor(s, off);
        q += __shfl_xor(q, off);
    }
    __shared__ float ss[4], sq[4];
    const int wid = tid >> 6, lane = tid & 63;
    if (lane == 0) { ss[wid] = s; sq[wid] = q; }
    __syncthreads();
    s = ss[0] + ss[1] + ss[2] + ss[3];
    q = sq[0] + sq[1] + sq[2] + sq[3];
    const float mu = s * (1.0f / 1024.0f);
    const float var = q * (1.0f / 1024.0f) - mu * mu;
    const float rs = rsqrtf(var + 1e-5f);
    const float4 gv = reinterpret_cast<const float4*>(g)[tid];
    const float4 bv = reinterpret_cast<const float4*>(b)[tid];
    u16x4 o;
    o[0] = f2bf((v.x - mu) * rs * gv.x + bv.x);
    o[1] = f2bf((v.y - mu) * rs * gv.y + bv.y);
    o[2] = f2bf((v.z - mu) * rs * gv.z + bv.z);
    o[3] = f2bf((v.w - mu) * rs * gv.w + bv.w);
    reinterpret_cast<u16x4*>(out + (size_t)row * 1024)[tid] = o;
}

// ---------------- Weight convert + transpose: W[K][N] fp32 -> Wt[N][K] bf16 ----------------
__global__ __launch_bounds__(256) void convT_kernel(
    const float* __restrict__ W, unsigned short* __restrict__ Wt, int K, int N)
{
    __shared__ float t[32][33];
    const int n0 = blockIdx.x * 32, k0 = blockIdx.y * 32;
    const int tx = threadIdx.x & 31;
    const int ty = threadIdx.x >> 5;  // 0..7
#pragma unroll
    for (int i = 0; i < 4; i++)
        t[ty + 8 * i][tx] = W[(size_t)(k0 + ty + 8 * i) * N + (n0 + tx)];
    __syncthreads();
#pragma unroll
    for (int i = 0; i < 4; i++)
        Wt[(size_t)(n0 + ty + 8 * i) * K + (k0 + tx)] = f2bf(t[tx][ty + 8 * i]);
}

// ---------------- bf16 MFMA GEMM: C[M][N] = A[M][K] * Wt[N][K]^T, fused epilogues ----------------
// EPI 0: out bf16          EPI 1: out fp32 = acc + resid
// EPI 2: out bf16 = gelu(acc + bias)      EPI 3: out fp32 = acc + bias + resid
template <int EPI>
__global__ __launch_bounds__(256) void gemm_kernel(
    const unsigned short* __restrict__ A, const unsigned short* __restrict__ Bt,
    const float* __restrict__ bias, const float* __restrict__ resid,
    void* __restrict__ out, int M, int N, int K)
{
    __shared__ unsigned short Al[128][72];
    __shared__ unsigned short Bl[128][72];
    const int tid = threadIdx.x;
    const int lane = tid & 63, wid = tid >> 6;
    const int wr = wid >> 1, wc = wid & 1;      // 2x2 waves over 128x128
    const int li = lane & 15, lg = lane >> 4;
    const int m0 = blockIdx.y * 128, n0 = blockIdx.x * 128;
    const int sr = tid >> 3;                    // 0..31 staging row
    const int sc = (tid & 7) * 8;               // 0..56 staging col
    f32x4 acc[4][4] = {};

    for (int k0 = 0; k0 < K; k0 += 64) {
        __syncthreads();
#pragma unroll
        for (int i = 0; i < 4; i++) {
            const int r = sr + 32 * i;
            *reinterpret_cast<u16x8*>(&Al[r][sc]) =
                *reinterpret_cast<const u16x8*>(&A[(size_t)(m0 + r) * K + k0 + sc]);
            *reinterpret_cast<u16x8*>(&Bl[r][sc]) =
                *reinterpret_cast<const u16x8*>(&Bt[(size_t)(n0 + r) * K + k0 + sc]);
        }
        __syncthreads();
#pragma unroll
        for (int ks = 0; ks < 2; ks++) {
            const int kof = ks * 32 + lg * 8;
            bf16x8 af[4], bfr[4];
#pragma unroll
            for (int m = 0; m < 4; m++)
                af[m] = *reinterpret_cast<const bf16x8*>(&Al[wr * 64 + m * 16 + li][kof]);
#pragma unroll
            for (int n = 0; n < 4; n++)
                bfr[n] = *reinterpret_cast<const bf16x8*>(&Bl[wc * 64 + n * 16 + li][kof]);
#pragma unroll
            for (int m = 0; m < 4; m++)
#pragma unroll
                for (int n = 0; n < 4; n++)
                    acc[m][n] = __builtin_amdgcn_mfma_f32_16x16x32_bf16(af[m], bfr[n], acc[m][n], 0, 0, 0);
        }
    }

#pragma unroll
    for (int m = 0; m < 4; m++) {
#pragma unroll
        for (int r = 0; r < 4; r++) {
            const int row = m0 + wr * 64 + m * 16 + lg * 4 + r;
#pragma unroll
            for (int n = 0; n < 4; n++) {
                const int col = n0 + wc * 64 + n * 16 + li;
                float v = acc[m][n][r];
                if constexpr (EPI == 0) {
                    reinterpret_cast<unsigned short*>(out)[(size_t)row * N + col] = f2bf(v);
                } else if constexpr (EPI == 1) {
                    reinterpret_cast<float*>(out)[(size_t)row * N + col] =
                        v + resid[(size_t)row * N + col];
                } else if constexpr (EPI == 2) {
                    v += bias[col];
                    v = 0.5f * v * (1.0f + erff(v * 0.70710678118f));
                    reinterpret_cast<unsigned short*>(out)[(size_t)row * N + col] = f2bf(v);
                } else {
                    reinterpret_cast<float*>(out)[(size_t)row * N + col] =
                        v + bias[col] + resid[(size_t)row * N + col];
                }
            }
        }
    }
}

// ---------------- Flash attention (causal): Q,K,V bf16 [B*C][H*D] -> O bf16 [B*C][H*D] ----------------
// grid: (C/64, B*H). block: 256 (4 waves x 16 q-rows). KV tiles of 64 keys.
__global__ __launch_bounds__(256) void flash_kernel(
    const unsigned short* __restrict__ Q, const unsigned short* __restrict__ Kb,
    const unsigned short* __restrict__ Vb, unsigned short* __restrict__ O)
{
    constexpr int C = 2048, HD = 1024, D = 64;
    __shared__ unsigned short Kl[64][72];
    __shared__ unsigned short Vt[64][72];
    __shared__ unsigned short Pl[64][72];
    const int tid = threadIdx.x;
    const int lane = tid & 63, wid = tid >> 6;
    const int li = lane & 15, lg = lane >> 4;
    const int qt = blockIdx.x;
    const int bh = blockIdx.y;
    const int b = bh >> 4, h = bh & 15;
    const int q0 = qt * 64;
    const size_t base = ((size_t)b * C) * HD + (size_t)h * D;

    // Q fragments held in registers for the whole KV loop
    const int qrow = q0 + wid * 16 + li;
    bf16x8 qa0 = *reinterpret_cast<const bf16x8*>(&Q[base + (size_t)qrow * HD + lg * 8]);
    bf16x8 qa1 = *reinterpret_cast<const bf16x8*>(&Q[base + (size_t)qrow * HD + 32 + lg * 8]);

    f32x4 acc[4] = {};
    float mrun[4], lrun[4];
#pragma unroll
    for (int r = 0; r < 4; r++) { mrun[r] = -INFINITY; lrun[r] = 0.0f; }

    const int sr = tid >> 3;         // 0..31
    const int sc = (tid & 7) * 8;    // 0..56
    const int myrow0 = q0 + wid * 16 + lg * 4;

    for (int kt = 0; kt <= qt; kt++) {
        const int k0 = kt * 64;
        __syncthreads();
#pragma unroll
        for (int i = 0; i < 2; i++) {
            const int key = sr + 32 * i;
            const u16x8 kv = *reinterpret_cast<const u16x8*>(&Kb[base + (size_t)(k0 + key) * HD + sc]);
            *reinterpret_cast<u16x8*>(&Kl[key][sc]) = kv;
            const u16x8 vv = *reinterpret_cast<const u16x8*>(&Vb[base + (size_t)(k0 + key) * HD + sc]);
#pragma unroll
            for (int j = 0; j < 8; j++) Vt[sc + j][key] = vv[j];
        }
        __syncthreads();

        // S = Q K^T  (per wave: 16 q-rows x 64 keys)
        f32x4 s[4] = {};
#pragma unroll
        for (int n = 0; n < 4; n++) {
            const bf16x8 kb0 = *reinterpret_cast<const bf16x8*>(&Kl[n * 16 + li][lg * 8]);
            const bf16x8 kb1 = *reinterpret_cast<const bf16x8*>(&Kl[n * 16 + li][32 + lg * 8]);
            s[n] = __builtin_amdgcn_mfma_f32_16x16x32_bf16(qa0, kb0, s[n], 0, 0, 0);
            s[n] = __builtin_amdgcn_mfma_f32_16x16x32_bf16(qa1, kb1, s[n], 0, 0, 0);
        }

        // scale + causal mask + online softmax
        const bool diag = (kt == qt);
        float mt[4] = {-INFINITY, -INFINITY, -INFINITY, -INFINITY};
#pragma unroll
        for (int n = 0; n < 4; n++) {
            const int key = k0 + n * 16 + li;
#pragma unroll
            for (int r = 0; r < 4; r++) {
                float sv = s[n][r] * 0.125f;
                if (diag && key > myrow0 + r) sv = -INFINITY;
                s[n][r] = sv;
                mt[r] = fmaxf(mt[r], sv);
            }
        }
#pragma unroll
        for (int off = 1; off < 16; off <<= 1)
#pragma unroll
            for (int r = 0; r < 4; r++) mt[r] = fmaxf(mt[r], __shfl_xor(mt[r], off));

        float lp[4];
#pragma unroll
        for (int r = 0; r < 4; r++) {
            const float mn = fmaxf(mrun[r], mt[r]);
            const float al = __expf(mrun[r] - mn);
            mrun[r] = mn;
            lrun[r] *= al;
#pragma unroll
            for (int n = 0; n < 4; n++) acc[n][r] *= al;
            lp[r] = 0.0f;
        }
#pragma unroll
        for (int n = 0; n < 4; n++) {
#pragma unroll
            for (int r = 0; r < 4; r++) {
                const float pv = __expf(s[n][r] - mrun[r]);
                lp[r] += pv;
                Pl[wid * 16 + lg * 4 + r][n * 16 + li] = f2bf(pv);
            }
        }
#pragma unroll
        for (int off = 1; off < 16; off <<= 1)
#pragma unroll
            for (int r = 0; r < 4; r++) lp[r] += __shfl_xor(lp[r], off);
#pragma unroll
        for (int r = 0; r < 4; r++) lrun[r] += lp[r];

        __syncthreads();  // P visible; V/K stable until next stage

        // O += P V   (A = P from LDS, B = V^T from transposed stage)
#pragma unroll
        for (int ks = 0; ks < 2; ks++) {
            const bf16x8 pa = *reinterpret_cast<const bf16x8*>(&Pl[wid * 16 + li][ks * 32 + lg * 8]);
#pragma unroll
            for (int n = 0; n < 4; n++) {
                const bf16x8 vb = *reinterpret_cast<const bf16x8*>(&Vt[n * 16 + li][ks * 32 + lg * 8]);
                acc[n] = __builtin_amdgcn_mfma_f32_16x16x32_bf16(pa, vb, acc[n], 0, 0, 0);
            }
        }
    }

#pragma unroll
    for (int n = 0; n < 4; n++) {
#pragma unroll
        for (int r = 0; r < 4; r++) {
            const float v = acc[n][r] / lrun[r];
            const int row = myrow0 + r;
            O[base + (size_t)row * HD + n * 16 + li] = f2bf(v);
        }
    }
}

// ---------------- launch ----------------
extern "C" void kernel_launch(void* const* d_in, const int* in_sizes, int n_in,
                              void* d_out, int out_size, void* d_ws, size_t ws_size,
                              hipStream_t stream) {
    constexpr int B = 4, C = 2048, E = 1024, H = 16, FF = 4096;
    constexpr int M = B * C;  // 8192

    const float* x     = (const float*)d_in[0];
    const float* ln1_g = (const float*)d_in[1];
    const float* ln1_b = (const float*)d_in[2];
    const float* Wq    = (const float*)d_in[3];
    const float* Wk    = (const float*)d_in[4];
    const float* Wv    = (const float*)d_in[5];
    const float* Wo    = (const float*)d_in[6];
    const float* ln2_g = (const float*)d_in[7];
    const float* ln2_b = (const float*)d_in[8];
    const float* W1    = (const float*)d_in[9];
    const float* b1    = (const float*)d_in[10];
    const float* W2    = (const float*)d_in[11];
    const float* b2    = (const float*)d_in[12];

    char* p = (char*)d_ws;
    auto alloc = [&](size_t bytes) { void* r = (void*)p; p += (bytes + 255) & ~(size_t)255; return r; };
    unsigned short* WqT  = (unsigned short*)alloc((size_t)E * E * 2);
    unsigned short* WkT  = (unsigned short*)alloc((size_t)E * E * 2);
    unsigned short* WvT  = (unsigned short*)alloc((size_t)E * E * 2);
    unsigned short* WoT  = (unsigned short*)alloc((size_t)E * E * 2);
    unsigned short* W1T  = (unsigned short*)alloc((size_t)E * FF * 2);
    unsigned short* W2T  = (unsigned short*)alloc((size_t)FF * E * 2);
    unsigned short* hb   = (unsigned short*)alloc((size_t)M * E * 2);
    unsigned short* Qb   = (unsigned short*)alloc((size_t)M * E * 2);
    unsigned short* Kb   = (unsigned short*)alloc((size_t)M * E * 2);
    unsigned short* Vb   = (unsigned short*)alloc((size_t)M * E * 2);
    unsigned short* attn = (unsigned short*)alloc((size_t)M * E * 2);
    float*          x1   = (float*)alloc((size_t)M * E * 4);
    unsigned short* h2   = (unsigned short*)alloc((size_t)M * E * 2);
    unsigned short* ff   = (unsigned short*)alloc((size_t)M * FF * 2);

    // weight conversion / transpose
    convT_kernel<<<dim3(E / 32, E / 32), 256, 0, stream>>>(Wq, WqT, E, E);
    convT_kernel<<<dim3(E / 32, E / 32), 256, 0, stream>>>(Wk, WkT, E, E);
    convT_kernel<<<dim3(E / 32, E / 32), 256, 0, stream>>>(Wv, WvT, E, E);
    convT_kernel<<<dim3(E / 32, E / 32), 256, 0, stream>>>(Wo, WoT, E, E);
    convT_kernel<<<dim3(FF / 32, E / 32), 256, 0, stream>>>(W1, W1T, E, FF);
    convT_kernel<<<dim3(E / 32, FF / 32), 256, 0, stream>>>(W2, W2T, FF, E);

    // LN1
    ln_kernel<<<M, 256, 0, stream>>>(x, ln1_g, ln1_b, hb);

    // QKV projections
    gemm_kernel<0><<<dim3(E / 128, M / 128), 256, 0, stream>>>(hb, WqT, nullptr, nullptr, Qb, M, E, E);
    gemm_kernel<0><<<dim3(E / 128, M / 128), 256, 0, stream>>>(hb, WkT, nullptr, nullptr, Kb, M, E, E);
    gemm_kernel<0><<<dim3(E / 128, M / 128), 256, 0, stream>>>(hb, WvT, nullptr, nullptr, Vb, M, E, E);

    // attention
    flash_kernel<<<dim3(C / 64, B * H), 256, 0, stream>>>(Qb, Kb, Vb, attn);

    // output projection + residual
    gemm_kernel<1><<<dim3(E / 128, M / 128), 256, 0, stream>>>(attn, WoT, nullptr, x, x1, M, E, E);

    // LN2
    ln_kernel<<<M, 256, 0, stream>>>(x1, ln2_g, ln2_b, h2);

    // FFN
    gemm_kernel<2><<<dim3(FF / 128, M / 128), 256, 0, stream>>>(h2, W1T, b1, nullptr, ff, M, FF, E);
    gemm_kernel<3><<<dim3(E / 128, M / 128), 256, 0, stream>>>(ff, W2T, b2, x1, d_out, M, E, FF);
}